// Round 19
// baseline (376.939 us; speedup 1.0000x reference)
//
#include <hip/hip_runtime.h>
#include <hip/hip_bf16.h>

using f32x4  = float          __attribute__((ext_vector_type(4)));
using bf16x8 = __bf16         __attribute__((ext_vector_type(8)));
using u16x8  = unsigned short __attribute__((ext_vector_type(8)));

#define C_CH 512
#define H_IN 37
#define W_IN 50
#define NPOS 1850       // 37*50
#define NROI 512
#define DIN  25088      // 512*49
#define DFC  4096
#define NPAR 84
#define NCLS 21
#define KS_FC 4
#define KS_HEAD 16

// prep mega-kernel block ranges
#define PB_X  232                 // transpose_x: 29*8
#define PB_WH 2048                // fill_whead: 4096*128/256
#define PB_TOT (PB_X + PB_WH)     // 2280

__device__ __forceinline__ unsigned pack_bf16x2(float a, float b) {
    __hip_bfloat162 h;
    h.x = __float2bfloat16(a);
    h.y = __float2bfloat16(b);
    return *reinterpret_cast<unsigned*>(&h);
}

__device__ __forceinline__ void gload_lds16(const void* src, void* dst) {
    __builtin_amdgcn_global_load_lds(
        (const __attribute__((address_space(1))) void*)src,
        (__attribute__((address_space(3))) void*)dst, 16, 0, 0);
}

// ---------------------------------------------------------------------------
// Fused prep: transpose_x | fill Whp (fp32 [4096][128], Wp||Ws zero-padded).
// ---------------------------------------------------------------------------
__global__ __launch_bounds__(256) void prep_kernel(
        const float* __restrict__ x, float* __restrict__ xt,
        const float* __restrict__ Wp, const float* __restrict__ Ws,
        float* __restrict__ Whp) {
    __shared__ float tile[64][65];
    int b = blockIdx.x;
    int t = threadIdx.x;
    if (b < PB_X) {
        // x (512, 37, 50) fp32 -> xt (1850, 512) fp32
        int p0 = (b % 29) * 64;
        int c0 = (b / 29) * 64;
        int tc = t & 63, tr = t >> 6;
#pragma unroll
        for (int i = 0; i < 16; ++i) {
            int r = tr + i * 4;
            int p = p0 + tc;
            float v = 0.f;
            if (p < NPOS) v = x[(size_t)(c0 + r) * NPOS + p];
            tile[r][tc] = v;
        }
        __syncthreads();
#pragma unroll
        for (int i = 0; i < 16; ++i) {
            int rw = tr + i * 4;
            int p = p0 + rw;
            if (p < NPOS) xt[(size_t)p * C_CH + c0 + tc] = tile[tc][rw];
        }
    } else {
        // Whp[k][c] fp32: c<84 -> Wp[k][c]; c<105 -> Ws[k][c-84]; else 0
        int idx = (b - PB_X) * 256 + t;
        int k = idx >> 7, c = idx & 127;
        float v = 0.f;
        if (c < NPAR) v = Wp[(size_t)k * NPAR + c];
        else if (c < NPAR + NCLS) v = Ws[(size_t)k * NCLS + (c - NPAR)];
        Whp[idx] = v;
    }
}

// ---------------------------------------------------------------------------
// RoI max-pool.  One block (256 thr) per ROI; thread t owns channels 2t,2t+1.
// pooled layout: [n][bin*512 + ch] bf16 (K-permuted; gemm1 permutes W1 rows).
// ---------------------------------------------------------------------------
__global__ __launch_bounds__(256) void roi_pool_kernel(
        const float* __restrict__ xt, const float* __restrict__ rois,
        __hip_bfloat16* __restrict__ pooled) {
    int n = blockIdx.x;
    int t = threadIdx.x;
    float4 rv = reinterpret_cast<const float4*>(rois)[n];
    int x1 = (int)fminf(fmaxf(rintf(rv.x * 0.0625f), 0.f), (float)W_IN);
    int y1 = (int)fminf(fmaxf(rintf(rv.y * 0.0625f), 0.f), (float)H_IN);
    int x2 = (int)fminf(fmaxf(rintf(rv.z * 0.0625f), 0.f), (float)W_IN);
    int y2 = (int)fminf(fmaxf(rintf(rv.w * 0.0625f), 0.f), (float)H_IN);
    bool valid = (x1 < x2) && (y1 < y2);
    unsigned* outp = reinterpret_cast<unsigned*>(pooled) + (size_t)n * (DIN / 2);
    if (!valid) {
        for (int b = 0; b < 49; ++b) outp[b * 256 + t] = 0u;
        return;
    }
    int x2e = min(x2, W_IN - 1), y2e = min(y2, H_IN - 1);
    int Hc = y2e - y1 + 1, Wc = x2e - x1 + 1;
    const float2* base = reinterpret_cast<const float2*>(xt);
    for (int i = 0; i < 7; ++i) {
        int rs = y1 + (i * Hc) / 7;
        int re = y1 + ((i + 1) * Hc + 6) / 7;
        for (int j = 0; j < 7; ++j) {
            int cs = x1 + (j * Wc) / 7;
            int ce = x1 + ((j + 1) * Wc + 6) / 7;
            float m0 = -__builtin_inff(), m1 = -__builtin_inff();
            for (int r = rs; r < re; ++r) {
                const float2* rowp = base + (size_t)r * (W_IN * C_CH / 2) + t;
                for (int c = cs; c < ce; ++c) {
                    float2 v = rowp[c * (C_CH / 2)];
                    m0 = fmaxf(m0, v.x);
                    m1 = fmaxf(m1, v.y);
                }
            }
            outp[(i * 7 + j) * 256 + t] = pack_bf16x2(m0, m1);
        }
    }
}

// ---------------------------------------------------------------------------
// bf16-A x fp32-B GEMM, 128x256 tile (R19): BK=64, 8 waves (2m x 4n, 512
// thr), per-wave 64x64 out, 16x16x32 MFMA.  R16 pipeline verbatim: lA
// triple-buffered 3x16KB (A staged 2 tiles ahead via global_load_lds), lB
// double-buffered 2x32KB (fp32 reg-load 8x f32x4 -> cvt_pk -> swizzled
// ds_write one tile ahead), ONE barrier/iter with counted s_waitcnt
// vmcnt(10): A(t+2):2 + B(t+2):8 stay in flight.  The 2x-wide tile halves
// system-wide barrier-iterations (the invariant ~2.4us/iter cost).
// LDS 112KB -> 1 block/CU, 8 waves = 2 waves/SIMD (same TLP as R16).
// acc 64 + v 32 + frags ~190 VGPR < 256 cap (launch_bounds(512), NO
// min-waves hint -- the spill trigger).  XOR swizzle ((r^(r>>3))&7)<<4.
// perm=1: B row k' = bin*512+ch maps to source row ch*49+bin (RoI-k permute).
// Cp: [KS][Mtot][N] fp32 split-K partials.  XCD-chunked block swizzle.
// ---------------------------------------------------------------------------
__global__ __launch_bounds__(512) void gemm_w256_kernel(
        const __hip_bfloat16* __restrict__ A,
        const float* __restrict__ Bf,
        float* __restrict__ Cp,
        int N, int lda, int ldbn, int kChunk, int nMT, int nNT, int Mtot,
        int perm) {
    __shared__ __align__(16) char lA[3 * 16384];
    __shared__ __align__(16) char lB[2 * 32768];
    int q = gridDim.x >> 3;
    int bid = (blockIdx.x & 7) * q + (blockIdx.x >> 3);
    int mt = bid % nMT;
    int nt = (bid / nMT) % nNT;
    int ks = bid / (nMT * nNT);
    int m0 = mt * 128, n0 = nt * 256;
    int k0 = ks * kChunk;
    int t = threadIdx.x;
    int lane = t & 63, wid = t >> 6;

    // A staging: 512 thr x 16B = 8KB/pass, 2 passes per 16KB tile.
    const char* srcA[2]; int offA[2];
#pragma unroll
    for (int i = 0; i < 2; ++i) {
        int p = t * 16 + i * 8192;
        int row = p >> 7;
        int swz = ((row ^ (row >> 3)) & 7) << 4;
        srcA[i] = (const char*)A + ((size_t)(m0 + row) * lda + k0) * 2
                  + ((p & 127) ^ swz);
        offA[i] = p;
    }
    auto stageA = [&](int buf) {
#pragma unroll
        for (int i = 0; i < 2; ++i) {
            gload_lds16(srcA[i], lA + buf * 16384 + offA[i]);
            srcA[i] += 128;          // next 64-k tile
        }
    };

    // B staging: thread owns n-rows (n4..n4+3) x k (k8..k8+7)
    int n4 = (t & 63) * 4;           // 0..252
    int k8 = (t >> 6) * 8;           // 0..56
    int woff[4];
#pragma unroll
    for (int j = 0; j < 4; ++j) {
        int row = n4 + j;
        int swz = ((row ^ (row >> 3)) & 7) << 4;
        woff[j] = row * 128 + ((k8 * 2) ^ swz);
    }
    const float* Bbase = Bf + n0 + n4;
    f32x4 v[8];
    auto loadB = [&](int kt) {
        int kb = k0 + kt * 64;
        int rbase = perm ? ((kb & 511) * 49 + (kb >> 9)) : kb;
        int rstr  = perm ? 49 : 1;
#pragma unroll
        for (int p = 0; p < 8; ++p)
            v[p] = *reinterpret_cast<const f32x4*>(
                Bbase + (size_t)(rbase + (k8 + p) * rstr) * ldbn);
    };
    auto cvtB = [&](int buf) {
#pragma unroll
        for (int j = 0; j < 4; ++j) {
            uint4 w;
            w.x = pack_bf16x2(v[0][j], v[1][j]);
            w.y = pack_bf16x2(v[2][j], v[3][j]);
            w.z = pack_bf16x2(v[4][j], v[5][j]);
            w.w = pack_bf16x2(v[6][j], v[7][j]);
            *reinterpret_cast<uint4*>(lB + buf * 32768 + woff[j]) = w;
        }
    };

    // fragment read offsets: wave grid 2m x 4n; per-wave 64x64 output
    int wm = wid >> 2, wn = wid & 3;
    int kb0 = (lane >> 4) << 4;
    int roA[4], roB[4], sA[4], sB[4];
#pragma unroll
    for (int f = 0; f < 4; ++f) {
        int ra = wm * 64 + f * 16 + (lane & 15);
        roA[f] = ra * 128; sA[f] = ((ra ^ (ra >> 3)) & 7) << 4;
        int rb = wn * 64 + f * 16 + (lane & 15);
        roB[f] = rb * 128; sB[f] = ((rb ^ (rb >> 3)) & 7) << 4;
    }

    f32x4 acc[4][4] = {};
    auto mfmaStep = [&](int aBuf, int bBuf) {
        const char* baseA = lA + aBuf * 16384;
        const char* baseB = lB + bBuf * 32768;
#pragma unroll
        for (int ksub = 0; ksub < 2; ++ksub) {
            int kk = kb0 | (ksub << 6);
            bf16x8 af[4], bfr[4];
#pragma unroll
            for (int f = 0; f < 4; ++f)
                af[f] = *reinterpret_cast<const bf16x8*>(baseA + roA[f] + (kk ^ sA[f]));
#pragma unroll
            for (int f = 0; f < 4; ++f)
                bfr[f] = *reinterpret_cast<const bf16x8*>(baseB + roB[f] + (kk ^ sB[f]));
#pragma unroll
            for (int mf = 0; mf < 4; ++mf)
#pragma unroll
                for (int nf = 0; nf < 4; ++nf)
                    acc[mf][nf] = __builtin_amdgcn_mfma_f32_16x16x32_bf16(
                        af[mf], bfr[nf], acc[mf][nf], 0, 0, 0);
        }
    };

    int nkt = kChunk >> 6;

    // prologue: A(0),A(1) staged; B(0) -> lB[0]; B(1) loads in flight
    stageA(0);
    stageA(1);
    loadB(0);
    cvtB(0);                       // reg-dep wait drains A0,A1,B0
    loadB(1);
    asm volatile("s_waitcnt vmcnt(8) lgkmcnt(0)\ns_barrier" ::: "memory");

    // steady state: straight-line body, one barrier, nothing drains
    int aCur = 0, aStage = 2, bCur = 0;
    for (int kt = 0; kt + 2 < nkt; ++kt) {
        stageA(aStage);            // A(kt+2): 2 DMA
        mfmaStep(aCur, bCur);      // compute tile kt
        cvtB(bCur ^ 1);            // B(kt+1) regs -> LDS (covered by MFMA)
        loadB(kt + 2);             // B(kt+2): 8 loads
        asm volatile("s_waitcnt vmcnt(10) lgkmcnt(0)\ns_barrier" ::: "memory");
        aCur = aCur == 2 ? 0 : aCur + 1;
        aStage = aStage == 2 ? 0 : aStage + 1;
        bCur ^= 1;
    }
    // kt = nkt-2: no staging left
    mfmaStep(aCur, bCur);
    cvtB(bCur ^ 1);
    asm volatile("s_waitcnt vmcnt(0) lgkmcnt(0)\ns_barrier" ::: "memory");
    aCur = aCur == 2 ? 0 : aCur + 1;
    bCur ^= 1;
    // kt = nkt-1: compute only
    mfmaStep(aCur, bCur);

    float* outp = Cp + (size_t)ks * Mtot * N;
    int rbase = m0 + wm * 64;
    int cbase = n0 + wn * 64 + (lane & 15);
    int rl = (lane >> 4) * 4;
#pragma unroll
    for (int mf = 0; mf < 4; ++mf)
#pragma unroll
        for (int nf = 0; nf < 4; ++nf)
#pragma unroll
            for (int r = 0; r < 4; ++r)
                outp[(size_t)(rbase + mf * 16 + rl + r) * N + cbase + nf * 16] =
                    acc[mf][nf][r];
}

// ---------------------------------------------------------------------------
// bf16-A x fp32-B GEMM, 128x128 tile (R16 best) -- head GEMM only (N=128).
// ---------------------------------------------------------------------------
__global__ __launch_bounds__(512, 2) void gemm_f32b_kernel(
        const __hip_bfloat16* __restrict__ A,
        const float* __restrict__ Bf,
        float* __restrict__ Cp,
        int N, int lda, int ldbn, int kChunk, int nMT, int nNT, int Mtot,
        int perm) {
    __shared__ __align__(16) char lA[3 * 16384];
    __shared__ __align__(16) char lB[2 * 16384];
    int q = gridDim.x >> 3;
    int bid = (blockIdx.x & 7) * q + (blockIdx.x >> 3);
    int mt = bid % nMT;
    int nt = (bid / nMT) % nNT;
    int ks = bid / (nMT * nNT);
    int m0 = mt * 128, n0 = nt * 128;
    int k0 = ks * kChunk;
    int t = threadIdx.x;
    int lane = t & 63, wid = t >> 6;

    const char* srcA[2]; int offA[2];
#pragma unroll
    for (int i = 0; i < 2; ++i) {
        int p = t * 16 + i * 8192;
        int row = p >> 7;
        int swz = ((row ^ (row >> 3)) & 7) << 4;
        srcA[i] = (const char*)A + ((size_t)(m0 + row) * lda + k0) * 2
                  + ((p & 127) ^ swz);
        offA[i] = p;
    }
    auto stageA = [&](int buf) {
#pragma unroll
        for (int i = 0; i < 2; ++i) {
            gload_lds16(srcA[i], lA + buf * 16384 + offA[i]);
            srcA[i] += 128;
        }
    };

    int n4 = (t & 31) * 4;
    int kq = (t >> 5) * 4;
    int woff[4];
#pragma unroll
    for (int j = 0; j < 4; ++j) {
        int row = n4 + j;
        int swz = ((row ^ (row >> 3)) & 7) << 4;
        woff[j] = row * 128 + ((kq * 2) ^ swz);
    }
    const float* Bbase = Bf + n0 + n4;
    f32x4 v[4];
    auto loadB = [&](int kt) {
        int kb = k0 + kt * 64;
        int rbase = perm ? ((kb & 511) * 49 + (kb >> 9)) : kb;
        int rstr  = perm ? 49 : 1;
#pragma unroll
        for (int p = 0; p < 4; ++p)
            v[p] = *reinterpret_cast<const f32x4*>(
                Bbase + (size_t)(rbase + (kq + p) * rstr) * ldbn);
    };
    auto cvtB = [&](int buf) {
#pragma unroll
        for (int j = 0; j < 4; ++j) {
            uint2 w;
            w.x = pack_bf16x2(v[0][j], v[1][j]);
            w.y = pack_bf16x2(v[2][j], v[3][j]);
            *reinterpret_cast<uint2*>(lB + buf * 16384 + woff[j]) = w;
        }
    };

    int wm = wid >> 2, wn = wid & 3;
    int kb0 = (lane >> 4) << 4;
    int roA[4], roB[2], sA[4], sB[2];
#pragma unroll
    for (int f = 0; f < 4; ++f) {
        int ra = wm * 64 + f * 16 + (lane & 15);
        roA[f] = ra * 128; sA[f] = ((ra ^ (ra >> 3)) & 7) << 4;
    }
#pragma unroll
    for (int f = 0; f < 2; ++f) {
        int rb = wn * 32 + f * 16 + (lane & 15);
        roB[f] = rb * 128; sB[f] = ((rb ^ (rb >> 3)) & 7) << 4;
    }

    f32x4 acc[4][2] = {};
    auto mfmaStep = [&](int aBuf, int bBuf) {
        const char* baseA = lA + aBuf * 16384;
        const char* baseB = lB + bBuf * 16384;
#pragma unroll
        for (int ksub = 0; ksub < 2; ++ksub) {
            int kk = kb0 | (ksub << 6);
            bf16x8 af[4], bfr[2];
#pragma unroll
            for (int f = 0; f < 4; ++f)
                af[f] = *reinterpret_cast<const bf16x8*>(baseA + roA[f] + (kk ^ sA[f]));
#pragma unroll
            for (int f = 0; f < 2; ++f)
                bfr[f] = *reinterpret_cast<const bf16x8*>(baseB + roB[f] + (kk ^ sB[f]));
#pragma unroll
            for (int mf = 0; mf < 4; ++mf)
#pragma unroll
                for (int nf = 0; nf < 2; ++nf)
                    acc[mf][nf] = __builtin_amdgcn_mfma_f32_16x16x32_bf16(
                        af[mf], bfr[nf], acc[mf][nf], 0, 0, 0);
        }
    };

    int nkt = kChunk >> 6;

    stageA(0);
    stageA(1);
    loadB(0);
    cvtB(0);
    loadB(1);
    asm volatile("s_waitcnt vmcnt(4) lgkmcnt(0)\ns_barrier" ::: "memory");

    int aCur = 0, aStage = 2, bCur = 0;
    for (int kt = 0; kt + 2 < nkt; ++kt) {
        stageA(aStage);
        mfmaStep(aCur, bCur);
        cvtB(bCur ^ 1);
        loadB(kt + 2);
        asm volatile("s_waitcnt vmcnt(6) lgkmcnt(0)\ns_barrier" ::: "memory");
        aCur = aCur == 2 ? 0 : aCur + 1;
        aStage = aStage == 2 ? 0 : aStage + 1;
        bCur ^= 1;
    }
    mfmaStep(aCur, bCur);
    cvtB(bCur ^ 1);
    asm volatile("s_waitcnt vmcnt(0) lgkmcnt(0)\ns_barrier" ::: "memory");
    aCur = aCur == 2 ? 0 : aCur + 1;
    bCur ^= 1;
    mfmaStep(aCur, bCur);

    float* outp = Cp + (size_t)ks * Mtot * N;
    int rbase = m0 + wm * 64;
    int cbase = n0 + wn * 32 + (lane & 15);
    int rl = (lane >> 4) * 4;
#pragma unroll
    for (int mf = 0; mf < 4; ++mf)
#pragma unroll
        for (int nf = 0; nf < 2; ++nf)
#pragma unroll
            for (int r = 0; r < 4; ++r)
                outp[(size_t)(rbase + mf * 16 + rl + r) * N + cbase + nf * 16] =
                    acc[mf][nf][r];
}

// ---------------------------------------------------------------------------
// Sum KS split-K partials + bias, ReLU, convert to bf16.
// ---------------------------------------------------------------------------
__global__ __launch_bounds__(256) void reduce_bias_relu_kernel(
        const float* __restrict__ P, const float* __restrict__ bias,
        __hip_bfloat16* __restrict__ out, int MN, int N, int KS) {
    int idx = blockIdx.x * blockDim.x + threadIdx.x;
    int e0 = idx * 4;
    if (e0 >= MN) return;
    f32x4 s = *reinterpret_cast<const f32x4*>(P + e0);
    for (int k = 1; k < KS; ++k)
        s += *reinterpret_cast<const f32x4*>(P + (size_t)k * MN + e0);
    f32x4 b = *reinterpret_cast<const f32x4*>(bias + (e0 & (N - 1)));
    s += b;
    uint2 pk;
    pk.x = pack_bf16x2(fmaxf(s[0], 0.f), fmaxf(s[1], 0.f));
    pk.y = pack_bf16x2(fmaxf(s[2], 0.f), fmaxf(s[3], 0.f));
    *reinterpret_cast<uint2*>(reinterpret_cast<char*>(out) + (size_t)e0 * 2) = pk;
}

// ---------------------------------------------------------------------------
// Sum KS_HEAD head partials + bias, scatter to (params, scores) output layout.
// P: [KS_HEAD][NROI][128] fp32.
// ---------------------------------------------------------------------------
__global__ __launch_bounds__(128) void head_reduce_kernel(
        const float* __restrict__ P, const float* __restrict__ bp,
        const float* __restrict__ bs, float* __restrict__ out) {
    int n = blockIdx.x, c = threadIdx.x;
    float s = 0.f;
#pragma unroll
    for (int ks = 0; ks < KS_HEAD; ++ks)
        s += P[(size_t)ks * NROI * 128 + (size_t)n * 128 + c];
    if (c < NPAR)
        out[(size_t)n * NPAR + c] = s + bp[c];
    else if (c < NPAR + NCLS)
        out[(size_t)NROI * NPAR + (size_t)n * NCLS + (c - NPAR)] = s + bs[c - NPAR];
}

// ---------------------------------------------------------------------------
extern "C" void kernel_launch(void* const* d_in, const int* in_sizes, int n_in,
                              void* d_out, int out_size, void* d_ws, size_t ws_size,
                              hipStream_t stream) {
    const float* x    = (const float*)d_in[0];
    const float* rois = (const float*)d_in[1];
    // d_in[2] roi_index: B=1 -> always 0, unused
    const float* W1 = (const float*)d_in[3];
    const float* b1 = (const float*)d_in[4];
    const float* W2 = (const float*)d_in[5];
    const float* b2 = (const float*)d_in[6];
    const float* Wp = (const float*)d_in[7];
    const float* bp = (const float*)d_in[8];
    const float* Ws = (const float*)d_in[9];
    const float* bs = (const float*)d_in[10];
    float* out = (float*)d_out;

    const size_t MB = 1ull << 20;
    char* ws = (char*)d_ws;
    float*          xt     = (float*)(ws + 0);                  // 3.62 MB
    __hip_bfloat16* pooled = (__hip_bfloat16*)(ws + 4   * MB);  // 24.5 MB
    float*          Whp    = (float*)(ws + 30  * MB);           // 2 MB
    float*          part   = (float*)(ws + 34  * MB);           // <= 34 MB
    __hip_bfloat16* fc6    = (__hip_bfloat16*)(ws + 104 * MB);  // 4 MB
    __hip_bfloat16* fc7    = (__hip_bfloat16*)(ws + 109 * MB);  // 4 MB

    prep_kernel<<<PB_TOT, 256, 0, stream>>>(x, xt, Wp, Ws, Whp);
    roi_pool_kernel<<<NROI, 256, 0, stream>>>(xt, rois, pooled);

    // fc6 = relu(pooled @ W1 + b1): M=512 N=4096 K=25088, 128x256 tile,
    // split-K=4 -> 256 blocks (1/CU), perm
    gemm_w256_kernel<<<4 * 16 * KS_FC, 512, 0, stream>>>(
        pooled, W1, part, DFC, DIN, DFC, DIN / KS_FC, 4, 16, NROI, 1);
    reduce_bias_relu_kernel<<<2048, 256, 0, stream>>>(part, b1, fc6,
                                                      NROI * DFC, DFC, KS_FC);

    // fc7 = relu(fc6 @ W2 + b2): M=512 N=4096 K=4096, 128x256 tile, split-K=4
    gemm_w256_kernel<<<4 * 16 * KS_FC, 512, 0, stream>>>(
        fc6, W2, part, DFC, DFC, DFC, DFC / KS_FC, 4, 16, NROI, 0);
    reduce_bias_relu_kernel<<<2048, 256, 0, stream>>>(part, b2, fc7,
                                                      NROI * DFC, DFC, KS_FC);

    // head = fc7 @ [Wp|Ws]: M=512 N=128(pad from 105) K=4096, split-K=16
    gemm_f32b_kernel<<<4 * KS_HEAD, 512, 0, stream>>>(
        fc7, Whp, part, 128, DFC, 128, DFC / KS_HEAD, 4, 1, NROI, 0);
    head_reduce_kernel<<<NROI, 128, 0, stream>>>(part, bp, bs, out);
}

// Round 20
// 338.078 us; speedup vs baseline: 1.1149x; 1.1149x over previous
//
#include <hip/hip_runtime.h>
#include <hip/hip_bf16.h>

using f32x4  = float          __attribute__((ext_vector_type(4)));
using bf16x8 = __bf16         __attribute__((ext_vector_type(8)));
using u16x8  = unsigned short __attribute__((ext_vector_type(8)));

#define C_CH 512
#define H_IN 37
#define W_IN 50
#define NPOS 1850       // 37*50
#define NROI 512
#define DIN  25088      // 512*49
#define DFC  4096
#define NPAR 84
#define NCLS 21
#define KS_FC 4
#define KS_HEAD 16

// prep mega-kernel block ranges
#define PB_X  232                 // transpose_x: 29*8
#define PB_WH 2048                // fill_whead: 4096*128/256
#define PB_TOT (PB_X + PB_WH)     // 2280

__device__ __forceinline__ unsigned pack_bf16x2(float a, float b) {
    __hip_bfloat162 h;
    h.x = __float2bfloat16(a);
    h.y = __float2bfloat16(b);
    return *reinterpret_cast<unsigned*>(&h);
}

__device__ __forceinline__ void gload_lds16(const void* src, void* dst) {
    __builtin_amdgcn_global_load_lds(
        (const __attribute__((address_space(1))) void*)src,
        (__attribute__((address_space(3))) void*)dst, 16, 0, 0);
}

// ---------------------------------------------------------------------------
// Fused prep: transpose_x | fill Whp (fp32 [4096][128], Wp||Ws zero-padded).
// ---------------------------------------------------------------------------
__global__ __launch_bounds__(256) void prep_kernel(
        const float* __restrict__ x, float* __restrict__ xt,
        const float* __restrict__ Wp, const float* __restrict__ Ws,
        float* __restrict__ Whp) {
    __shared__ float tile[64][65];
    int b = blockIdx.x;
    int t = threadIdx.x;
    if (b < PB_X) {
        // x (512, 37, 50) fp32 -> xt (1850, 512) fp32
        int p0 = (b % 29) * 64;
        int c0 = (b / 29) * 64;
        int tc = t & 63, tr = t >> 6;
#pragma unroll
        for (int i = 0; i < 16; ++i) {
            int r = tr + i * 4;
            int p = p0 + tc;
            float v = 0.f;
            if (p < NPOS) v = x[(size_t)(c0 + r) * NPOS + p];
            tile[r][tc] = v;
        }
        __syncthreads();
#pragma unroll
        for (int i = 0; i < 16; ++i) {
            int rw = tr + i * 4;
            int p = p0 + rw;
            if (p < NPOS) xt[(size_t)p * C_CH + c0 + tc] = tile[tc][rw];
        }
    } else {
        // Whp[k][c] fp32: c<84 -> Wp[k][c]; c<105 -> Ws[k][c-84]; else 0
        int idx = (b - PB_X) * 256 + t;
        int k = idx >> 7, c = idx & 127;
        float v = 0.f;
        if (c < NPAR) v = Wp[(size_t)k * NPAR + c];
        else if (c < NPAR + NCLS) v = Ws[(size_t)k * NCLS + (c - NPAR)];
        Whp[idx] = v;
    }
}

// ---------------------------------------------------------------------------
// RoI max-pool.  One block (256 thr) per ROI; thread t owns channels 2t,2t+1.
// pooled layout: [n][bin*512 + ch] bf16 (K-permuted; gemm1 permutes W1 rows).
// ---------------------------------------------------------------------------
__global__ __launch_bounds__(256) void roi_pool_kernel(
        const float* __restrict__ xt, const float* __restrict__ rois,
        __hip_bfloat16* __restrict__ pooled) {
    int n = blockIdx.x;
    int t = threadIdx.x;
    float4 rv = reinterpret_cast<const float4*>(rois)[n];
    int x1 = (int)fminf(fmaxf(rintf(rv.x * 0.0625f), 0.f), (float)W_IN);
    int y1 = (int)fminf(fmaxf(rintf(rv.y * 0.0625f), 0.f), (float)H_IN);
    int x2 = (int)fminf(fmaxf(rintf(rv.z * 0.0625f), 0.f), (float)W_IN);
    int y2 = (int)fminf(fmaxf(rintf(rv.w * 0.0625f), 0.f), (float)H_IN);
    bool valid = (x1 < x2) && (y1 < y2);
    unsigned* outp = reinterpret_cast<unsigned*>(pooled) + (size_t)n * (DIN / 2);
    if (!valid) {
        for (int b = 0; b < 49; ++b) outp[b * 256 + t] = 0u;
        return;
    }
    int x2e = min(x2, W_IN - 1), y2e = min(y2, H_IN - 1);
    int Hc = y2e - y1 + 1, Wc = x2e - x1 + 1;
    const float2* base = reinterpret_cast<const float2*>(xt);
    for (int i = 0; i < 7; ++i) {
        int rs = y1 + (i * Hc) / 7;
        int re = y1 + ((i + 1) * Hc + 6) / 7;
        for (int j = 0; j < 7; ++j) {
            int cs = x1 + (j * Wc) / 7;
            int ce = x1 + ((j + 1) * Wc + 6) / 7;
            float m0 = -__builtin_inff(), m1 = -__builtin_inff();
            for (int r = rs; r < re; ++r) {
                const float2* rowp = base + (size_t)r * (W_IN * C_CH / 2) + t;
                for (int c = cs; c < ce; ++c) {
                    float2 v = rowp[c * (C_CH / 2)];
                    m0 = fmaxf(m0, v.x);
                    m1 = fmaxf(m1, v.y);
                }
            }
            outp[(i * 7 + j) * 256 + t] = pack_bf16x2(m0, m1);
        }
    }
}

// ---------------------------------------------------------------------------
// bf16-A x fp32-B GEMM, 256x128 tile (R20): BK=64, 8 waves (4m x 2n, 512
// thr), per-wave 64x64 out, 16x16x32 MFMA.  R16 pipeline verbatim: lA
// triple-buffered 3x32KB (A staged 2 tiles ahead via global_load_lds), lB
// double-buffered 2x16KB (fp32 reg-load 4x f32x4 -> cvt_pk -> swizzled
// ds_write one tile ahead), ONE barrier/iter with counted s_waitcnt
// vmcnt(8): A(t+2):4 + B(t+2):4 stay in flight.  BM=256 -> nMT=2: each
// W1 B-tile is requested by 2 blocks instead of 4 (the duplication test).
// LDS 128KB -> 1 block/CU, 8 waves = 2 waves/SIMD.  acc 64 + v 16 + misc
// ~180 VGPR < 256 cap (launch_bounds(512), NO min-waves hint).
// XOR swizzle ((r^(r>>3))&7)<<4.  perm=1: B row k' = bin*512+ch maps to
// source row ch*49+bin.  Cp: [KS][Mtot][N] fp32.  XCD-chunked swizzle.
// ---------------------------------------------------------------------------
__global__ __launch_bounds__(512) void gemm_m256_kernel(
        const __hip_bfloat16* __restrict__ A,
        const float* __restrict__ Bf,
        float* __restrict__ Cp,
        int N, int lda, int ldbn, int kChunk, int nMT, int nNT, int Mtot,
        int perm) {
    __shared__ __align__(16) char lA[3 * 32768];
    __shared__ __align__(16) char lB[2 * 16384];
    int q = gridDim.x >> 3;
    int bid = (blockIdx.x & 7) * q + (blockIdx.x >> 3);
    int mt = bid % nMT;
    int nt = (bid / nMT) % nNT;
    int ks = bid / (nMT * nNT);
    int m0 = mt * 256, n0 = nt * 128;
    int k0 = ks * kChunk;
    int t = threadIdx.x;
    int lane = t & 63, wid = t >> 6;

    // A staging: 512 thr x 16B x 4 passes = 32KB tile (256 rows x 128B).
    const char* srcA[4]; int offA[4];
#pragma unroll
    for (int i = 0; i < 4; ++i) {
        int p = t * 16 + i * 8192;
        int row = p >> 7;                  // 0..255
        int swz = ((row ^ (row >> 3)) & 7) << 4;
        srcA[i] = (const char*)A + ((size_t)(m0 + row) * lda + k0) * 2
                  + ((p & 127) ^ swz);
        offA[i] = p;
    }
    auto stageA = [&](int buf) {
#pragma unroll
        for (int i = 0; i < 4; ++i) {
            gload_lds16(srcA[i], lA + buf * 32768 + offA[i]);
            srcA[i] += 128;          // next 64-k tile
        }
    };

    // B staging: thread owns (n4..n4+3) x (kq..kq+3)
    int n4 = (t & 31) * 4;
    int kq = (t >> 5) * 4;           // 0..60
    int woff[4];
#pragma unroll
    for (int j = 0; j < 4; ++j) {
        int row = n4 + j;
        int swz = ((row ^ (row >> 3)) & 7) << 4;
        woff[j] = row * 128 + ((kq * 2) ^ swz);
    }
    const float* Bbase = Bf + n0 + n4;
    f32x4 v[4];
    auto loadB = [&](int kt) {
        int kb = k0 + kt * 64;
        int rbase = perm ? ((kb & 511) * 49 + (kb >> 9)) : kb;
        int rstr  = perm ? 49 : 1;
#pragma unroll
        for (int p = 0; p < 4; ++p)
            v[p] = *reinterpret_cast<const f32x4*>(
                Bbase + (size_t)(rbase + (kq + p) * rstr) * ldbn);
    };
    auto cvtB = [&](int buf) {
#pragma unroll
        for (int j = 0; j < 4; ++j) {
            uint2 w;
            w.x = pack_bf16x2(v[0][j], v[1][j]);
            w.y = pack_bf16x2(v[2][j], v[3][j]);
            *reinterpret_cast<uint2*>(lB + buf * 16384 + woff[j]) = w;
        }
    };

    // fragment read offsets: wave grid 4m x 2n; per-wave 64x64 output
    int wm = wid >> 1, wn = wid & 1;
    int kb0 = (lane >> 4) << 4;
    int roA[4], roB[4], sA[4], sB[4];
#pragma unroll
    for (int f = 0; f < 4; ++f) {
        int ra = wm * 64 + f * 16 + (lane & 15);
        roA[f] = ra * 128; sA[f] = ((ra ^ (ra >> 3)) & 7) << 4;
        int rb = wn * 64 + f * 16 + (lane & 15);
        roB[f] = rb * 128; sB[f] = ((rb ^ (rb >> 3)) & 7) << 4;
    }

    f32x4 acc[4][4] = {};
    auto mfmaStep = [&](int aBuf, int bBuf) {
        const char* baseA = lA + aBuf * 32768;
        const char* baseB = lB + bBuf * 16384;
#pragma unroll
        for (int ksub = 0; ksub < 2; ++ksub) {
            int kk = kb0 | (ksub << 6);
            bf16x8 af[4], bfr[4];
#pragma unroll
            for (int f = 0; f < 4; ++f)
                af[f] = *reinterpret_cast<const bf16x8*>(baseA + roA[f] + (kk ^ sA[f]));
#pragma unroll
            for (int f = 0; f < 4; ++f)
                bfr[f] = *reinterpret_cast<const bf16x8*>(baseB + roB[f] + (kk ^ sB[f]));
#pragma unroll
            for (int mf = 0; mf < 4; ++mf)
#pragma unroll
                for (int nf = 0; nf < 4; ++nf)
                    acc[mf][nf] = __builtin_amdgcn_mfma_f32_16x16x32_bf16(
                        af[mf], bfr[nf], acc[mf][nf], 0, 0, 0);
        }
    };

    int nkt = kChunk >> 6;

    // prologue: A(0),A(1) staged; B(0) -> lB[0]; B(1) loads in flight
    stageA(0);
    stageA(1);
    loadB(0);
    cvtB(0);                       // reg-dep wait drains A0,A1,B0
    loadB(1);
    asm volatile("s_waitcnt vmcnt(4) lgkmcnt(0)\ns_barrier" ::: "memory");

    // steady state: straight-line body, one barrier, nothing drains
    int aCur = 0, aStage = 2, bCur = 0;
    for (int kt = 0; kt + 2 < nkt; ++kt) {
        stageA(aStage);            // A(kt+2): 4 DMA
        mfmaStep(aCur, bCur);      // compute tile kt
        cvtB(bCur ^ 1);            // B(kt+1) regs -> LDS (covered by MFMA)
        loadB(kt + 2);             // B(kt+2): 4 loads
        asm volatile("s_waitcnt vmcnt(8) lgkmcnt(0)\ns_barrier" ::: "memory");
        aCur = aCur == 2 ? 0 : aCur + 1;
        aStage = aStage == 2 ? 0 : aStage + 1;
        bCur ^= 1;
    }
    // kt = nkt-2: no staging left
    mfmaStep(aCur, bCur);
    cvtB(bCur ^ 1);
    asm volatile("s_waitcnt vmcnt(0) lgkmcnt(0)\ns_barrier" ::: "memory");
    aCur = aCur == 2 ? 0 : aCur + 1;
    bCur ^= 1;
    // kt = nkt-1: compute only
    mfmaStep(aCur, bCur);

    float* outp = Cp + (size_t)ks * Mtot * N;
    int rbase = m0 + wm * 64;
    int cbase = n0 + wn * 64 + (lane & 15);
    int rl = (lane >> 4) * 4;
#pragma unroll
    for (int mf = 0; mf < 4; ++mf)
#pragma unroll
        for (int nf = 0; nf < 4; ++nf)
#pragma unroll
            for (int r = 0; r < 4; ++r)
                outp[(size_t)(rbase + mf * 16 + rl + r) * N + cbase + nf * 16] =
                    acc[mf][nf][r];
}

// ---------------------------------------------------------------------------
// bf16-A x fp32-B GEMM, 128x128 tile (R16 best) -- head GEMM only (N=128).
// ---------------------------------------------------------------------------
__global__ __launch_bounds__(512, 2) void gemm_f32b_kernel(
        const __hip_bfloat16* __restrict__ A,
        const float* __restrict__ Bf,
        float* __restrict__ Cp,
        int N, int lda, int ldbn, int kChunk, int nMT, int nNT, int Mtot,
        int perm) {
    __shared__ __align__(16) char lA[3 * 16384];
    __shared__ __align__(16) char lB[2 * 16384];
    int q = gridDim.x >> 3;
    int bid = (blockIdx.x & 7) * q + (blockIdx.x >> 3);
    int mt = bid % nMT;
    int nt = (bid / nMT) % nNT;
    int ks = bid / (nMT * nNT);
    int m0 = mt * 128, n0 = nt * 128;
    int k0 = ks * kChunk;
    int t = threadIdx.x;
    int lane = t & 63, wid = t >> 6;

    const char* srcA[2]; int offA[2];
#pragma unroll
    for (int i = 0; i < 2; ++i) {
        int p = t * 16 + i * 8192;
        int row = p >> 7;
        int swz = ((row ^ (row >> 3)) & 7) << 4;
        srcA[i] = (const char*)A + ((size_t)(m0 + row) * lda + k0) * 2
                  + ((p & 127) ^ swz);
        offA[i] = p;
    }
    auto stageA = [&](int buf) {
#pragma unroll
        for (int i = 0; i < 2; ++i) {
            gload_lds16(srcA[i], lA + buf * 16384 + offA[i]);
            srcA[i] += 128;
        }
    };

    int n4 = (t & 31) * 4;
    int kq = (t >> 5) * 4;
    int woff[4];
#pragma unroll
    for (int j = 0; j < 4; ++j) {
        int row = n4 + j;
        int swz = ((row ^ (row >> 3)) & 7) << 4;
        woff[j] = row * 128 + ((kq * 2) ^ swz);
    }
    const float* Bbase = Bf + n0 + n4;
    f32x4 v[4];
    auto loadB = [&](int kt) {
        int kb = k0 + kt * 64;
        int rbase = perm ? ((kb & 511) * 49 + (kb >> 9)) : kb;
        int rstr  = perm ? 49 : 1;
#pragma unroll
        for (int p = 0; p < 4; ++p)
            v[p] = *reinterpret_cast<const f32x4*>(
                Bbase + (size_t)(rbase + (kq + p) * rstr) * ldbn);
    };
    auto cvtB = [&](int buf) {
#pragma unroll
        for (int j = 0; j < 4; ++j) {
            uint2 w;
            w.x = pack_bf16x2(v[0][j], v[1][j]);
            w.y = pack_bf16x2(v[2][j], v[3][j]);
            *reinterpret_cast<uint2*>(lB + buf * 16384 + woff[j]) = w;
        }
    };

    int wm = wid >> 2, wn = wid & 3;
    int kb0 = (lane >> 4) << 4;
    int roA[4], roB[2], sA[4], sB[2];
#pragma unroll
    for (int f = 0; f < 4; ++f) {
        int ra = wm * 64 + f * 16 + (lane & 15);
        roA[f] = ra * 128; sA[f] = ((ra ^ (ra >> 3)) & 7) << 4;
    }
#pragma unroll
    for (int f = 0; f < 2; ++f) {
        int rb = wn * 32 + f * 16 + (lane & 15);
        roB[f] = rb * 128; sB[f] = ((rb ^ (rb >> 3)) & 7) << 4;
    }

    f32x4 acc[4][2] = {};
    auto mfmaStep = [&](int aBuf, int bBuf) {
        const char* baseA = lA + aBuf * 16384;
        const char* baseB = lB + bBuf * 16384;
#pragma unroll
        for (int ksub = 0; ksub < 2; ++ksub) {
            int kk = kb0 | (ksub << 6);
            bf16x8 af[4], bfr[2];
#pragma unroll
            for (int f = 0; f < 4; ++f)
                af[f] = *reinterpret_cast<const bf16x8*>(baseA + roA[f] + (kk ^ sA[f]));
#pragma unroll
            for (int f = 0; f < 2; ++f)
                bfr[f] = *reinterpret_cast<const bf16x8*>(baseB + roB[f] + (kk ^ sB[f]));
#pragma unroll
            for (int mf = 0; mf < 4; ++mf)
#pragma unroll
                for (int nf = 0; nf < 2; ++nf)
                    acc[mf][nf] = __builtin_amdgcn_mfma_f32_16x16x32_bf16(
                        af[mf], bfr[nf], acc[mf][nf], 0, 0, 0);
        }
    };

    int nkt = kChunk >> 6;

    stageA(0);
    stageA(1);
    loadB(0);
    cvtB(0);
    loadB(1);
    asm volatile("s_waitcnt vmcnt(4) lgkmcnt(0)\ns_barrier" ::: "memory");

    int aCur = 0, aStage = 2, bCur = 0;
    for (int kt = 0; kt + 2 < nkt; ++kt) {
        stageA(aStage);
        mfmaStep(aCur, bCur);
        cvtB(bCur ^ 1);
        loadB(kt + 2);
        asm volatile("s_waitcnt vmcnt(6) lgkmcnt(0)\ns_barrier" ::: "memory");
        aCur = aCur == 2 ? 0 : aCur + 1;
        aStage = aStage == 2 ? 0 : aStage + 1;
        bCur ^= 1;
    }
    mfmaStep(aCur, bCur);
    cvtB(bCur ^ 1);
    asm volatile("s_waitcnt vmcnt(0) lgkmcnt(0)\ns_barrier" ::: "memory");
    aCur = aCur == 2 ? 0 : aCur + 1;
    bCur ^= 1;
    mfmaStep(aCur, bCur);

    float* outp = Cp + (size_t)ks * Mtot * N;
    int rbase = m0 + wm * 64;
    int cbase = n0 + wn * 32 + (lane & 15);
    int rl = (lane >> 4) * 4;
#pragma unroll
    for (int mf = 0; mf < 4; ++mf)
#pragma unroll
        for (int nf = 0; nf < 2; ++nf)
#pragma unroll
            for (int r = 0; r < 4; ++r)
                outp[(size_t)(rbase + mf * 16 + rl + r) * N + cbase + nf * 16] =
                    acc[mf][nf][r];
}

// ---------------------------------------------------------------------------
// Sum KS split-K partials + bias, ReLU, convert to bf16.
// ---------------------------------------------------------------------------
__global__ __launch_bounds__(256) void reduce_bias_relu_kernel(
        const float* __restrict__ P, const float* __restrict__ bias,
        __hip_bfloat16* __restrict__ out, int MN, int N, int KS) {
    int idx = blockIdx.x * blockDim.x + threadIdx.x;
    int e0 = idx * 4;
    if (e0 >= MN) return;
    f32x4 s = *reinterpret_cast<const f32x4*>(P + e0);
    for (int k = 1; k < KS; ++k)
        s += *reinterpret_cast<const f32x4*>(P + (size_t)k * MN + e0);
    f32x4 b = *reinterpret_cast<const f32x4*>(bias + (e0 & (N - 1)));
    s += b;
    uint2 pk;
    pk.x = pack_bf16x2(fmaxf(s[0], 0.f), fmaxf(s[1], 0.f));
    pk.y = pack_bf16x2(fmaxf(s[2], 0.f), fmaxf(s[3], 0.f));
    *reinterpret_cast<uint2*>(reinterpret_cast<char*>(out) + (size_t)e0 * 2) = pk;
}

// ---------------------------------------------------------------------------
// Sum KS_HEAD head partials + bias, scatter to (params, scores) output layout.
// P: [KS_HEAD][NROI][128] fp32.
// ---------------------------------------------------------------------------
__global__ __launch_bounds__(128) void head_reduce_kernel(
        const float* __restrict__ P, const float* __restrict__ bp,
        const float* __restrict__ bs, float* __restrict__ out) {
    int n = blockIdx.x, c = threadIdx.x;
    float s = 0.f;
#pragma unroll
    for (int ks = 0; ks < KS_HEAD; ++ks)
        s += P[(size_t)ks * NROI * 128 + (size_t)n * 128 + c];
    if (c < NPAR)
        out[(size_t)n * NPAR + c] = s + bp[c];
    else if (c < NPAR + NCLS)
        out[(size_t)NROI * NPAR + (size_t)n * NCLS + (c - NPAR)] = s + bs[c - NPAR];
}

// ---------------------------------------------------------------------------
extern "C" void kernel_launch(void* const* d_in, const int* in_sizes, int n_in,
                              void* d_out, int out_size, void* d_ws, size_t ws_size,
                              hipStream_t stream) {
    const float* x    = (const float*)d_in[0];
    const float* rois = (const float*)d_in[1];
    // d_in[2] roi_index: B=1 -> always 0, unused
    const float* W1 = (const float*)d_in[3];
    const float* b1 = (const float*)d_in[4];
    const float* W2 = (const float*)d_in[5];
    const float* b2 = (const float*)d_in[6];
    const float* Wp = (const float*)d_in[7];
    const float* bp = (const float*)d_in[8];
    const float* Ws = (const float*)d_in[9];
    const float* bs = (const float*)d_in[10];
    float* out = (float*)d_out;

    const size_t MB = 1ull << 20;
    char* ws = (char*)d_ws;
    float*          xt     = (float*)(ws + 0);                  // 3.62 MB
    __hip_bfloat16* pooled = (__hip_bfloat16*)(ws + 4   * MB);  // 24.5 MB
    float*          Whp    = (float*)(ws + 30  * MB);           // 2 MB
    float*          part   = (float*)(ws + 34  * MB);           // <= 34 MB
    __hip_bfloat16* fc6    = (__hip_bfloat16*)(ws + 104 * MB);  // 4 MB
    __hip_bfloat16* fc7    = (__hip_bfloat16*)(ws + 109 * MB);  // 4 MB

    prep_kernel<<<PB_TOT, 256, 0, stream>>>(x, xt, Wp, Ws, Whp);
    roi_pool_kernel<<<NROI, 256, 0, stream>>>(xt, rois, pooled);

    // fc6 = relu(pooled @ W1 + b1): M=512 N=4096 K=25088, 256x128 tile,
    // split-K=4 -> 256 blocks (nMT=2: halved B duplication), perm
    gemm_m256_kernel<<<2 * 32 * KS_FC, 512, 0, stream>>>(
        pooled, W1, part, DFC, DIN, DFC, DIN / KS_FC, 2, 32, NROI, 1);
    reduce_bias_relu_kernel<<<2048, 256, 0, stream>>>(part, b1, fc6,
                                                      NROI * DFC, DFC, KS_FC);

    // fc7 = relu(fc6 @ W2 + b2): M=512 N=4096 K=4096, 256x128 tile, split-K=4
    gemm_m256_kernel<<<2 * 32 * KS_FC, 512, 0, stream>>>(
        fc6, W2, part, DFC, DFC, DFC, DFC / KS_FC, 2, 32, NROI, 0);
    reduce_bias_relu_kernel<<<2048, 256, 0, stream>>>(part, b2, fc7,
                                                      NROI * DFC, DFC, KS_FC);

    // head = fc7 @ [Wp|Ws]: M=512 N=128(pad from 105) K=4096, split-K=16
    gemm_f32b_kernel<<<4 * KS_HEAD, 512, 0, stream>>>(
        fc7, Whp, part, 128, DFC, 128, DFC / KS_HEAD, 4, 1, NROI, 0);
    head_reduce_kernel<<<NROI, 128, 0, stream>>>(part, bp, bs, out);
}